// Round 6
// baseline (29.212 us; speedup 1.0000x reference)
//
#include <hip/hip_runtime.h>

// Batched 4x4 symmetric eigenvalues via cyclic Jacobi (values only).
// One THREAD = TWO matrices (ILP: two independent dependency chains hide
// v_sqrt/v_rcp/v_rsq latency; R5 showed ~160cy/rotation vs ~52cy static
// issue -> latency-bound). H diag = concat(E1,E2); strict upper = C in
// row-major pair order (0,1),(0,2),(0,3),(1,2),(1,3),(2,3).
//
// R4: approx instrs v_rcp/v_sqrt/v_rsq (50->29.8us).
// R5: folded sign, launch_bounds(256,8), cond sweep 5 (->25.9us).
// R6: 2 mats/thread + 3 mandatory sweeps + <=2 conditional sweeps
//     + diag-only 2x2 polish (exact pair eigenvalues, no row updates).

#define ROT(p, q, r0, r1)                                                   \
    {                                                                       \
        float apq = a[p][q];                                                \
        float h = a[q][q] - a[p][p];                                        \
        float u = apq + apq;                                                \
        float r = __builtin_amdgcn_sqrtf(fmaf(u, u, h * h)) + 1e-30f;       \
        float d = h + copysignf(r, h);                                      \
        float t = u * __builtin_amdgcn_rcpf(d);                             \
        float c = __builtin_amdgcn_rsqf(fmaf(t, t, 1.0f));                  \
        float s = t * c;                                                    \
        a[p][p] = fmaf(-t, apq, a[p][p]);                                   \
        a[q][q] = fmaf(t, apq, a[q][q]);                                    \
        a[p][q] = 0.0f; a[q][p] = 0.0f;                                     \
        {                                                                   \
            float arp = a[r0][p], arq = a[r0][q];                           \
            a[r0][p] = a[p][r0] = fmaf(c, arp, -s * arq);                   \
            a[r0][q] = a[q][r0] = fmaf(s, arp, c * arq);                    \
        }                                                                   \
        {                                                                   \
            float arp = a[r1][p], arq = a[r1][q];                           \
            a[r1][p] = a[p][r1] = fmaf(c, arp, -s * arq);                   \
            a[r1][q] = a[q][r1] = fmaf(s, arp, c * arq);                    \
        }                                                                   \
    }

// Diagonal-only exact 2x2 eigen-shift: same t as ROT but skips row updates
// and c,s (saves v_rsq + 12 VALU). Off-diags left stale (O(eps), ignored).
#define POLISH(p, q)                                                        \
    {                                                                       \
        float apq = a[p][q];                                                \
        float h = a[q][q] - a[p][p];                                        \
        float u = apq + apq;                                                \
        float r = __builtin_amdgcn_sqrtf(fmaf(u, u, h * h)) + 1e-30f;       \
        float d = h + copysignf(r, h);                                      \
        float t = u * __builtin_amdgcn_rcpf(d);                             \
        a[p][p] = fmaf(-t, apq, a[p][p]);                                   \
        a[q][q] = fmaf(t, apq, a[q][q]);                                    \
    }

__device__ __forceinline__ void sweep4(float (&a)[4][4])
{
    ROT(0, 1, 2, 3);
    ROT(0, 2, 1, 3);
    ROT(0, 3, 1, 2);
    ROT(1, 2, 0, 3);
    ROT(1, 3, 0, 2);
    ROT(2, 3, 0, 1);
}

__device__ __forceinline__ float offnorm2(const float (&a)[4][4])
{
    float o = a[0][1] * a[0][1];
    o = fmaf(a[0][2], a[0][2], o);
    o = fmaf(a[0][3], a[0][3], o);
    o = fmaf(a[1][2], a[1][2], o);
    o = fmaf(a[1][3], a[1][3], o);
    o = fmaf(a[2][3], a[2][3], o);
    return o;
}

__device__ __forceinline__ void polish4(float (&a)[4][4])
{
    POLISH(0, 1); POLISH(0, 2); POLISH(0, 3);
    POLISH(1, 2); POLISH(1, 3); POLISH(2, 3);
}

__device__ __forceinline__ float4 sorted_diag(const float (&a)[4][4])
{
    float w = a[0][0], x = a[1][1], y = a[2][2], z = a[3][3];
#define CSWAP(u, v) { float lo = fminf(u, v), hi = fmaxf(u, v); u = lo; v = hi; }
    CSWAP(w, x); CSWAP(y, z); CSWAP(w, y); CSWAP(x, z); CSWAP(x, y);
#undef CSWAP
    return make_float4(w, x, y, z);
}

__global__ __launch_bounds__(256, 8) void eig4_jacobi_kernel(
    const float* __restrict__ E1,
    const float* __restrict__ E2,
    const float* __restrict__ C,
    float* __restrict__ out,
    int Bhalf)  // = B/2 threads, 2 matrices each
{
    int t = blockIdx.x * blockDim.x + threadIdx.x;
    if (t >= Bhalf) return;

    // Wide vector loads covering BOTH matrices (16B aligned everywhere).
    float4 e1 = *reinterpret_cast<const float4*>(E1 + 4 * t);  // m0.e1, m1.e1
    float4 e2 = *reinterpret_cast<const float4*>(E2 + 4 * t);
    const float4* c4 = reinterpret_cast<const float4*>(C + 12 * t);
    float4 cA = c4[0];  // m0: c01 c02 c03 c12
    float4 cB = c4[1];  // m0: c13 c23 | m1: c01 c02
    float4 cC = c4[2];  // m1: c03 c12 c13 c23

    float a0[4][4], a1[4][4];
    a0[0][0] = e1.x; a0[1][1] = e1.y; a0[2][2] = e2.x; a0[3][3] = e2.y;
    a0[0][1] = a0[1][0] = cA.x;
    a0[0][2] = a0[2][0] = cA.y;
    a0[0][3] = a0[3][0] = cA.z;
    a0[1][2] = a0[2][1] = cA.w;
    a0[1][3] = a0[3][1] = cB.x;
    a0[2][3] = a0[3][2] = cB.y;

    a1[0][0] = e1.z; a1[1][1] = e1.w; a1[2][2] = e2.z; a1[3][3] = e2.w;
    a1[0][1] = a1[1][0] = cB.z;
    a1[0][2] = a1[2][0] = cB.w;
    a1[0][3] = a1[3][0] = cC.x;
    a1[1][2] = a1[2][1] = cC.y;
    a1[1][3] = a1[3][1] = cC.z;
    a1[2][3] = a1[3][2] = cC.w;

    // 3 mandatory sweeps; the two chains are independent -> ILP.
    #pragma unroll
    for (int sweep = 0; sweep < 3; ++sweep) {
        { float (&a)[4][4] = a0; sweep4(a); }
        { float (&a)[4][4] = a1; sweep4(a); }
    }

    // Up to 2 conditional sweeps, wave-uniform. Tol: off2 < 1e-6 means
    // off-norm < 1e-3 -> lambda error <= 1e-3 (Weyl), and the polish
    // below reduces it to second order. Budget: 0.156 - 0.031 observed.
    float o = fmaxf(offnorm2(a0), offnorm2(a1));
    if (!__all(o < 1e-6f)) {
        { float (&a)[4][4] = a0; sweep4(a); }
        { float (&a)[4][4] = a1; sweep4(a); }
        o = fmaxf(offnorm2(a0), offnorm2(a1));
        if (!__all(o < 1e-6f)) {
            { float (&a)[4][4] = a0; sweep4(a); }
            { float (&a)[4][4] = a1; sweep4(a); }
        }
    }

    // Diagonal-only polish: exact 2x2 eigenvalues per pair, second-order
    // cleanup of the remaining off-diagonal mass.
    { float (&a)[4][4] = a0; polish4(a); }
    { float (&a)[4][4] = a1; polish4(a); }

    float4 r0 = sorted_diag(a0);
    float4 r1 = sorted_diag(a1);
    float4* o4 = reinterpret_cast<float4*>(out + 8 * t);
    o4[0] = r0;
    o4[1] = r1;
}

extern "C" void kernel_launch(void* const* d_in, const int* in_sizes, int n_in,
                              void* d_out, int out_size, void* d_ws, size_t ws_size,
                              hipStream_t stream)
{
    const float* E1 = (const float*)d_in[0];
    const float* E2 = (const float*)d_in[1];
    const float* C  = (const float*)d_in[2];
    float* out = (float*)d_out;

    int B = in_sizes[0] / 2;       // E1 is [B, 2]
    int Bhalf = B / 2;             // B = 2^20, even
    int block = 256;
    int grid = (Bhalf + block - 1) / block;
    eig4_jacobi_kernel<<<grid, block, 0, stream>>>(E1, E2, C, out, Bhalf);
}

// Round 7
// 25.953 us; speedup vs baseline: 1.1255x; 1.1255x over previous
//
#include <hip/hip_runtime.h>

// Batched 4x4 symmetric eigenvalues, one thread = one matrix.
// H diag = concat(E1,E2); strict upper = C in row-major pair order
// (0,1),(0,2),(0,3),(1,2),(1,3),(2,3).
//
// R4: approx v_rcp/v_sqrt/v_rsq (50->29.8us).
// R5: folded sign, launch_bounds(256,8), conditional sweep 5 (->25.9us).
// R6: 2 mats/thread REGRESSED (->29.2us): 128-wide vote + VGPR cap killed it.
// R7: parallel-ordered Jacobi: sweep = 3 stages x 2 DISJOINT pivots
//     -> the two (c,s) transcendental chains per stage overlap (2-way ILP
//     within one matrix, no extra register state). rcp-free rotation:
//     d = h+copysign(r,h); d^2+u^2 = 2r|d| exactly, so
//     ws = copysign(rsq(2r|d|), d), c = d*ws, s = u*ws (c^2+s^2=1),
//     diag via g = c*u - s*h: a_pp -= s*g, a_qq += s*g (exact 2x2 form).
//     u nudged by copysign(1e-15,u): keeps 2r|d| >= 2e-30 (no FTZ blowup),
//     degenerate block becomes a harmless exact 45-degree rotation.

// One stage: two independent rotations on disjoint pivots (p,q) and (r_,s_),
// then the shared 2x2 cross-block sandwich B' = R1^T B R2.
#define STAGE(p, q, r_, s_)                                                 \
    {                                                                       \
        float h1 = a[q][q] - a[p][p];                                       \
        float h2 = a[s_][s_] - a[r_][r_];                                   \
        float u1 = a[p][q] + a[p][q];                                       \
        float u2 = a[r_][s_] + a[r_][s_];                                   \
        u1 = u1 + copysignf(1e-15f, u1);                                    \
        u2 = u2 + copysignf(1e-15f, u2);                                    \
        float rr1 = __builtin_amdgcn_sqrtf(fmaf(u1, u1, h1 * h1));          \
        float rr2 = __builtin_amdgcn_sqrtf(fmaf(u2, u2, h2 * h2));          \
        float d1 = h1 + copysignf(rr1, h1);                                 \
        float d2 = h2 + copysignf(rr2, h2);                                 \
        float w1 = __builtin_amdgcn_rsqf((rr1 + rr1) * fabsf(d1));          \
        float w2 = __builtin_amdgcn_rsqf((rr2 + rr2) * fabsf(d2));          \
        float ws1 = copysignf(w1, d1);                                      \
        float ws2 = copysignf(w2, d2);                                      \
        float c1 = d1 * ws1, s1 = u1 * ws1;                                 \
        float c2 = d2 * ws2, s2 = u2 * ws2;                                 \
        float g1 = fmaf(-s1, h1, c1 * u1);                                  \
        float g2 = fmaf(-s2, h2, c2 * u2);                                  \
        a[p][p]   = fmaf(-s1, g1, a[p][p]);                                 \
        a[q][q]   = fmaf( s1, g1, a[q][q]);                                 \
        a[r_][r_] = fmaf(-s2, g2, a[r_][r_]);                               \
        a[s_][s_] = fmaf( s2, g2, a[s_][s_]);                               \
        a[p][q] = a[q][p] = 0.0f;                                           \
        a[r_][s_] = a[s_][r_] = 0.0f;                                       \
        float bpr = a[p][r_], bps = a[p][s_];                               \
        float bqr = a[q][r_], bqs = a[q][s_];                               \
        float tpr = fmaf(c1, bpr, -(s1 * bqr));                             \
        float tps = fmaf(c1, bps, -(s1 * bqs));                             \
        float tqr = fmaf(s1, bpr, c1 * bqr);                                \
        float tqs = fmaf(s1, bps, c1 * bqs);                                \
        a[p][r_] = a[r_][p] = fmaf(c2, tpr, -(s2 * tps));                   \
        a[p][s_] = a[s_][p] = fmaf(s2, tpr, c2 * tps);                      \
        a[q][r_] = a[r_][q] = fmaf(c2, tqr, -(s2 * tqs));                   \
        a[q][s_] = a[s_][q] = fmaf(s2, tqr, c2 * tqs);                      \
    }

// Round-robin sweep: all 6 pivots in 3 stages of disjoint pairs.
#define SWEEP                                                               \
    STAGE(0, 1, 2, 3);                                                      \
    STAGE(0, 2, 1, 3);                                                      \
    STAGE(0, 3, 1, 2);

__global__ __launch_bounds__(256, 8) void eig4_jacobi_kernel(
    const float* __restrict__ E1,
    const float* __restrict__ E2,
    const float* __restrict__ C,
    float* __restrict__ out,
    int B)
{
    int i = blockIdx.x * blockDim.x + threadIdx.x;
    if (i >= B) return;

    // Coalesced vector loads: 8B-aligned for every i.
    float2 e1 = *reinterpret_cast<const float2*>(E1 + 2 * i);
    float2 e2 = *reinterpret_cast<const float2*>(E2 + 2 * i);
    const float2* c2 = reinterpret_cast<const float2*>(C + 6 * i);
    float2 ca = c2[0];
    float2 cb = c2[1];
    float2 cc = c2[2];

    // Full symmetric 4x4 in registers (constant indices only).
    float a[4][4];
    a[0][0] = e1.x; a[1][1] = e1.y; a[2][2] = e2.x; a[3][3] = e2.y;
    a[0][1] = a[1][0] = ca.x;   // (0,1)
    a[0][2] = a[2][0] = ca.y;   // (0,2)
    a[0][3] = a[3][0] = cb.x;   // (0,3)
    a[1][2] = a[2][1] = cb.y;   // (1,2)
    a[1][3] = a[3][1] = cc.x;   // (1,3)
    a[2][3] = a[3][2] = cc.y;   // (2,3)

    // 4 mandatory sweeps, then sweep 5 only if some lane hasn't converged
    // (tol proven in R5: almost always skipped, absmax 0.03125).
    SWEEP; SWEEP; SWEEP; SWEEP;

    float off2 = a[0][1] * a[0][1];
    off2 = fmaf(a[0][2], a[0][2], off2);
    off2 = fmaf(a[0][3], a[0][3], off2);
    off2 = fmaf(a[1][2], a[1][2], off2);
    off2 = fmaf(a[1][3], a[1][3], off2);
    off2 = fmaf(a[2][3], a[2][3], off2);
    if (!__all(off2 < 1e-8f)) {
        SWEEP;
    }

    float w = a[0][0], x = a[1][1], y = a[2][2], z = a[3][3];

    // Ascending sort, 5-comparator network.
#define CSWAP(u, v) { float lo = fminf(u, v), hi = fmaxf(u, v); u = lo; v = hi; }
    CSWAP(w, x); CSWAP(y, z); CSWAP(w, y); CSWAP(x, z); CSWAP(x, y);
#undef CSWAP

    *reinterpret_cast<float4*>(out + 4 * i) = make_float4(w, x, y, z);
}

extern "C" void kernel_launch(void* const* d_in, const int* in_sizes, int n_in,
                              void* d_out, int out_size, void* d_ws, size_t ws_size,
                              hipStream_t stream)
{
    const float* E1 = (const float*)d_in[0];
    const float* E2 = (const float*)d_in[1];
    const float* C  = (const float*)d_in[2];
    float* out = (float*)d_out;

    int B = in_sizes[0] / 2;  // E1 is [B, 2]
    int block = 256;
    int grid = (B + block - 1) / block;
    eig4_jacobi_kernel<<<grid, block, 0, stream>>>(E1, E2, C, out, B);
}

// Round 8
// 25.301 us; speedup vs baseline: 1.1546x; 1.0258x over previous
//
#include <hip/hip_runtime.h>

// Batched 4x4 symmetric eigenvalues. One THREAD = TWO matrices, packed as
// lanes .x/.y of float2 ext-vectors -> every rotation op becomes a packed
// full-rate v_pk_{fma,mul,add}_f32 (VOP3P, CDNA dual-FP32). Transcendentals
// (v_sqrt/v_rsq/v_rcp) have no pk form: 2 scalar ops per packed step.
//
// History: R4 approx-trans (50->29.8), R5 folded sign+occupancy+cond-sweep
// (->25.9), R6 2-mat scalar REGRESSED (29.2: 128-wide vote + serial chains),
// R7 parallel-order neutral (25.95: issue-bound, not latency-bound).
// R8: packed-lane 2-mat, R7's rcp-free rotation math (proven), R5's
// sequential pivot order (proven), FIXED 4 sweeps (no vote), diag-only
// polish (R6-proven) as tail cleanup. bf16-compared output (absmax floor
// 0.03125) leaves wide accuracy margin.

typedef float v2 __attribute__((ext_vector_type(2)));

__device__ __forceinline__ v2 v2fma(v2 a, v2 b, v2 c) {
    return __builtin_elementwise_fma(a, b, c);
}
__device__ __forceinline__ v2 v2cps(v2 mag, v2 sgn) {
    return __builtin_elementwise_copysign(mag, sgn);
}
__device__ __forceinline__ v2 v2abs(v2 x) {
    return __builtin_elementwise_abs(x);
}
__device__ __forceinline__ v2 v2sqrt(v2 x) {
    v2 r; r.x = __builtin_amdgcn_sqrtf(x.x); r.y = __builtin_amdgcn_sqrtf(x.y); return r;
}
__device__ __forceinline__ v2 v2rsq(v2 x) {
    v2 r; r.x = __builtin_amdgcn_rsqf(x.x); r.y = __builtin_amdgcn_rsqf(x.y); return r;
}
__device__ __forceinline__ v2 v2rcp(v2 x) {
    v2 r; r.x = __builtin_amdgcn_rcpf(x.x); r.y = __builtin_amdgcn_rcpf(x.y); return r;
}

// Full Jacobi rotation zeroing opq (both packed matrices at once).
// R7-proven rcp-free math: u nudged so m = 2r|d| >= 2e-30 (normal, no FTZ);
// ws = copysign(rsq(m), d); c = d*ws, s = u*ws (c^2+s^2 = 1 exactly via
// d^2+u^2 = 2r|d|); diag shift g = c*u - s*h. x0p/x0q, x1p/x1q are the
// cross elements (row r0, row r1) at columns p,q.
#define ROT(dp, dq, opq, x0p, x0q, x1p, x1q)                                \
    {                                                                       \
        v2 apq = opq;                                                       \
        v2 h = dq - dp;                                                     \
        v2 u = apq + apq;                                                   \
        u = u + v2cps((v2)1e-15f, u);                                       \
        v2 r = v2sqrt(v2fma(u, u, h * h));                                  \
        v2 d = h + v2cps(r, h);                                             \
        v2 m = (r + r) * v2abs(d);                                          \
        v2 ws = v2cps(v2rsq(m), d);                                         \
        v2 c = d * ws;                                                      \
        v2 s = u * ws;                                                      \
        v2 g = v2fma(-s, h, c * u);                                         \
        dp = v2fma(-s, g, dp);                                              \
        dq = v2fma(s, g, dq);                                               \
        opq = (v2)0.0f;                                                     \
        v2 n0p = v2fma(c, x0p, -(s * x0q));                                 \
        v2 n0q = v2fma(s, x0p, c * x0q);                                    \
        x0p = n0p; x0q = n0q;                                               \
        v2 n1p = v2fma(c, x1p, -(s * x1q));                                 \
        v2 n1q = v2fma(s, x1p, c * x1q);                                    \
        x1p = n1p; x1q = n1q;                                               \
    }

// Diagonal-only exact 2x2 eigen-shift (R6-proven): second-order cleanup of
// residual off-diagonal mass, no row updates. Guard: r+1e-30 so d != 0.
#define POLISH(dp, dq, opq)                                                 \
    {                                                                       \
        v2 apq = opq;                                                       \
        v2 h = dq - dp;                                                     \
        v2 u = apq + apq;                                                   \
        v2 r = v2sqrt(v2fma(u, u, h * h)) + (v2)1e-30f;                     \
        v2 d = h + v2cps(r, h);                                             \
        v2 t = u * v2rcp(d);                                                \
        dp = v2fma(-t, apq, dp);                                            \
        dq = v2fma(t, apq, dq);                                             \
    }

// Sequential cyclic sweep (R5-proven order). Cross pairs per pivot (p,q):
// rows r0<r1 are the other two indices; element (r,c) with r<c is o_rc.
#define SWEEP                                                               \
    ROT(d0, d1, o01, o02, o12, o03, o13);                                   \
    ROT(d0, d2, o02, o01, o12, o03, o23);                                   \
    ROT(d0, d3, o03, o01, o13, o02, o23);                                   \
    ROT(d1, d2, o12, o01, o02, o13, o23);                                   \
    ROT(d1, d3, o13, o01, o03, o12, o23);                                   \
    ROT(d2, d3, o23, o02, o03, o12, o13);

__global__ __launch_bounds__(256, 8) void eig4_jacobi_kernel(
    const float* __restrict__ E1,
    const float* __restrict__ E2,
    const float* __restrict__ C,
    float* __restrict__ out,
    int Bhalf)  // B/2 threads, 2 matrices each
{
    int t = blockIdx.x * blockDim.x + threadIdx.x;
    if (t >= Bhalf) return;

    // Wide 16B loads covering both matrices (aligned for every t).
    float4 e1 = *reinterpret_cast<const float4*>(E1 + 4 * t);  // m0.E1, m1.E1
    float4 e2 = *reinterpret_cast<const float4*>(E2 + 4 * t);
    const float4* c4 = reinterpret_cast<const float4*>(C + 12 * t);
    float4 cA = c4[0];  // m0: c01 c02 c03 c12
    float4 cB = c4[1];  // m0: c13 c23 | m1: c01 c02
    float4 cC = c4[2];  // m1: c03 c12 c13 c23

    // Packed state: lane .x = matrix0, lane .y = matrix1. 10 v2 = 20 VGPR.
    v2 d0 = {e1.x, e1.z}, d1 = {e1.y, e1.w};
    v2 d2 = {e2.x, e2.z}, d3 = {e2.y, e2.w};
    v2 o01 = {cA.x, cB.z};
    v2 o02 = {cA.y, cB.w};
    v2 o03 = {cA.z, cC.x};
    v2 o12 = {cA.w, cC.y};
    v2 o13 = {cB.x, cC.z};
    v2 o23 = {cB.y, cC.w};

    // Fixed 4 sweeps (no vote -- R6's 128-wide vote was the regression),
    // then diag polish for the tail lanes that would have needed sweep 5.
    SWEEP; SWEEP; SWEEP; SWEEP;

    POLISH(d0, d1, o01);
    POLISH(d0, d2, o02);
    POLISH(d0, d3, o03);
    POLISH(d1, d2, o12);
    POLISH(d1, d3, o13);
    POLISH(d2, d3, o23);

    // Sort each matrix's diagonal ascending (scalar, 5 comparators each).
#define CSWAP(u, v) { float lo = fminf(u, v), hi = fmaxf(u, v); u = lo; v = hi; }
    {
        float w = d0.x, x = d1.x, y = d2.x, z = d3.x;
        CSWAP(w, x); CSWAP(y, z); CSWAP(w, y); CSWAP(x, z); CSWAP(x, y);
        reinterpret_cast<float4*>(out + 8 * t)[0] = make_float4(w, x, y, z);
    }
    {
        float w = d0.y, x = d1.y, y = d2.y, z = d3.y;
        CSWAP(w, x); CSWAP(y, z); CSWAP(w, y); CSWAP(x, z); CSWAP(x, y);
        reinterpret_cast<float4*>(out + 8 * t)[1] = make_float4(w, x, y, z);
    }
#undef CSWAP
}

extern "C" void kernel_launch(void* const* d_in, const int* in_sizes, int n_in,
                              void* d_out, int out_size, void* d_ws, size_t ws_size,
                              hipStream_t stream)
{
    const float* E1 = (const float*)d_in[0];
    const float* E2 = (const float*)d_in[1];
    const float* C  = (const float*)d_in[2];
    float* out = (float*)d_out;

    int B = in_sizes[0] / 2;   // E1 is [B, 2]
    int Bhalf = B / 2;         // B = 2^20, even
    int block = 256;
    int grid = (Bhalf + block - 1) / block;
    eig4_jacobi_kernel<<<grid, block, 0, stream>>>(E1, E2, C, out, Bhalf);
}

// Round 9
// 15.252 us; speedup vs baseline: 1.9153x; 1.6589x over previous
//
#include <hip/hip_runtime.h>

// Batched 4x4 symmetric eigenvalues via CLOSED-FORM quartic.
// One thread = one matrix. H diag = concat(E1,E2); strict upper = C in
// row-major pair order (0,1),(0,2),(0,3),(1,2),(1,3),(2,3).
//
// History: R3 baseline Jacobi 50us; R4 approx-trans 29.8; R5 25.9;
// R6 2-mat scalar regressed; R7 parallel-order neutral (issue-bound);
// R8 packed-f32 neutral (v_pk is NOT double-rate on gfx950 -- FP32 peak
// 157.3TF == scalar issue peak). Only lever left: algorithmic op count.
// R9: closed form. Shift traceless: B = H - m I, m = tr/4.
//   char poly: L^4 + p L^2 + q L + r, p = -tr(B^2)/2, q = -tr(B^3)/3,
//   r = det(B). Resolvent cubic z^3 + 2p z^2 + (p^2-4r) z - q^2 = 0 has
//   roots z_k = (Li+Lj)^2 >= 0 (pairings); trig solve (all-real).
//   L = copysign(.5,-q)*{s1+s2+s3, s1-s2-s3, s2-s1-s3, s3-s1-s2} + m,
//   s_k = sqrt(max(z_k,0)). Verified by hand: {2,-2,1,-1}, {3,1,0,-4}.
// Guards: every sqrt clamped >=0, acos arg clamped [-1,1], rcp(2R^3+1e-30)
// (B==0 -> t=0 -> all roots m, correct). q==0: product z_k = q^2 = 0
// forces a zero z -> both sign sets coincide (continuous).

__global__ __launch_bounds__(256, 8) void eig4_closed_kernel(
    const float* __restrict__ E1,
    const float* __restrict__ E2,
    const float* __restrict__ C,
    float* __restrict__ out,
    int B)
{
    int i = blockIdx.x * blockDim.x + threadIdx.x;
    if (i >= B) return;

    // Coalesced 8B loads (aligned for every i).
    float2 e1 = *reinterpret_cast<const float2*>(E1 + 2 * i);
    float2 e2 = *reinterpret_cast<const float2*>(E2 + 2 * i);
    const float2* c2 = reinterpret_cast<const float2*>(C + 6 * i);
    float2 ca = c2[0];
    float2 cb = c2[1];
    float2 cc = c2[2];
    float o01 = ca.x, o02 = ca.y, o03 = cb.x;
    float o12 = cb.y, o13 = cc.x, o23 = cc.y;

    // Shift to traceless: B = H - m I.
    float m = (e1.x + e1.y + e2.x + e2.y) * 0.25f;
    float b0 = e1.x - m, b1 = e1.y - m, b2 = e2.x - m, b3 = e2.y - m;

    // Invariants. p = -tr(B^2)/2.
    float q01 = o01 * o01, q02 = o02 * o02, q03 = o03 * o03;
    float q12 = o12 * o12, q13 = o13 * o13, q23 = o23 * o23;
    float soff = q01 + q02 + q03 + q12 + q13 + q23;
    float b0s = b0 * b0, b1s = b1 * b1, b2s = b2 * b2, b3s = b3 * b3;
    float tr2 = b0s + b1s + b2s + b3s + 2.0f * soff;
    float p = -0.5f * tr2;

    // q = -tr(B^3)/3; tr(B^3) = sum bi^3 + 3 sum (bi+bj) oij^2
    //                         + 6 (o01 o02 o12 + o01 o03 o13 + o02 o03 o23 + o12 o13 o23)
    float cub = b0s * b0 + b1s * b1 + b2s * b2 + b3s * b3;
    float mix = (b0 + b1) * q01 + (b0 + b2) * q02 + (b0 + b3) * q03
              + (b1 + b2) * q12 + (b1 + b3) * q13 + (b2 + b3) * q23;
    float tri = o01 * o02 * o12 + o01 * o03 * o13
              + o02 * o03 * o23 + o12 * o13 * o23;
    float tr3 = cub + 3.0f * mix + 6.0f * tri;
    float q = -tr3 * (1.0f / 3.0f);

    // r = det(B), cofactor expansion with CSE (hand-verified on 4 cases).
    float A1 = fmaf(b2, b3, -q23);
    float A2 = fmaf(o12, b3, -(o23 * o13));
    float A3 = fmaf(-b2, o13, o12 * o23);
    float A4 = fmaf(o02, b3, -(o23 * o03));
    float A5 = fmaf(-b2, o03, o02 * o23);
    float A6 = fmaf(o02, o13, -(o12 * o03));
    float M00 = b1 * A1 - o12 * A2 + o13 * A3;
    float M01 = o01 * A1 - o12 * A4 + o13 * A5;
    float M02 = o01 * A2 - b1 * A4 + o13 * A6;
    float M03 = o01 * A3 - b1 * A5 + o12 * A6;
    float r = b0 * M00 - o01 * M01 + o02 * M02 - o03 * M03;

    // Depressed resolvent cubic: w^3 + P w + Q, z = w - 2p/3.
    // P = -p^2/3 - 4r ; Q = -2p^3/27 + 8pr/3 - q^2. All roots real (P<=0).
    float pp = p * p;
    float P = fmaf(pp, -(1.0f / 3.0f), -4.0f * r);
    float Q = fmaf(p, fmaf(pp, -(2.0f / 27.0f), (8.0f / 3.0f) * r), -(q * q));
    float R2 = fmaxf(P * (-1.0f / 3.0f), 0.0f);
    float R = __builtin_amdgcn_sqrtf(R2);
    float R3 = R2 * R;
    // cos(3 phi) = -Q / (2 R^3), guarded for R == 0 (B == 0 -> t = 0).
    float t = -Q * __builtin_amdgcn_rcpf(fmaf(2.0f, R3, 1e-30f));
    t = fminf(fmaxf(t, -1.0f), 1.0f);
    float phi = acosf(t) * (1.0f / 3.0f);        // [0, pi/3]
    float cph = cosf(phi);                        // [0.5, 1]
    float sph = __builtin_amdgcn_sqrtf(fmaxf(fmaf(-cph, cph, 1.0f), 0.0f));
    float Rc = R * cph;
    float Rs = R * sph * 1.7320508f;              // sqrt(3) R sin(phi)
    float u0 = p * (-2.0f / 3.0f);
    float z1 = fmaf(2.0f, Rc, u0);                // w1 = 2 R cos(phi)
    float z2 = u0 - Rc - Rs;                      // w = 2 R cos(phi+2pi/3)
    float z3 = u0 - Rc + Rs;                      // w = 2 R cos(phi-2pi/3)
    float s1 = __builtin_amdgcn_sqrtf(fmaxf(z1, 0.0f));
    float s2 = __builtin_amdgcn_sqrtf(fmaxf(z2, 0.0f));
    float s3 = __builtin_amdgcn_sqrtf(fmaxf(z3, 0.0f));

    // Quartic roots: sign triples with product = -sign(q).
    float hh = copysignf(0.5f, -q);
    float w = fmaf(hh, s1 + s2 + s3, m);
    float x = fmaf(hh, s1 - s2 - s3, m);
    float y = fmaf(hh, s2 - s1 - s3, m);
    float z = fmaf(hh, s3 - s1 - s2, m);

    // Ascending sort, 5-comparator network.
#define CSWAP(u, v) { float lo = fminf(u, v), hi = fmaxf(u, v); u = lo; v = hi; }
    CSWAP(w, x); CSWAP(y, z); CSWAP(w, y); CSWAP(x, z); CSWAP(x, y);
#undef CSWAP

    *reinterpret_cast<float4*>(out + 4 * i) = make_float4(w, x, y, z);
}

extern "C" void kernel_launch(void* const* d_in, const int* in_sizes, int n_in,
                              void* d_out, int out_size, void* d_ws, size_t ws_size,
                              hipStream_t stream)
{
    const float* E1 = (const float*)d_in[0];
    const float* E2 = (const float*)d_in[1];
    const float* C  = (const float*)d_in[2];
    float* out = (float*)d_out;

    int B = in_sizes[0] / 2;  // E1 is [B, 2]
    int block = 256;
    int grid = (B + block - 1) / block;
    eig4_closed_kernel<<<grid, block, 0, stream>>>(E1, E2, C, out, B);
}

// Round 11
// 15.140 us; speedup vs baseline: 1.9294x; 1.0074x over previous
//
#include <hip/hip_runtime.h>

// Batched 4x4 symmetric eigenvalues via CLOSED-FORM quartic.
// One thread = one matrix. H diag = concat(E1,E2); strict upper = C in
// row-major pair order (0,1),(0,2),(0,3),(1,2),(1,3),(2,3).
//
// History: R3 Jacobi 50us -> R4 29.8 (approx trans) -> R5 25.9 (occupancy,
// cond sweep) -> R7/R8 neutral (issue-slot-bound; v_pk not double-rate on
// gfx950) -> R9 closed-form quartic 15.25us.
// R10: kill the two libm calls. acosf -> Hastings A&S 4.4.46
//   acos(x) = sqrt(1-x)*P7(x), |err|<=2e-8 rad, branchless reflection for
//   x<0 (exact at endpoints: double-root cases). cosf/sinf -> HW v_cos/v_sin
//   (input in REVOLUTIONS): phi_rev = acos(t)*(1/(6*pi)) in [0,1/6], no
//   range reduction. HW trig err ~1e-6 -> lambda err << bf16 floor (0.03125).
//
// Math (R9-proven): B = H - m I (m = tr/4) traceless; char poly
// L^4 + p L^2 + q L + r; resolvent cubic z^3 + 2p z^2 + (p^2-4r) z - q^2
// has roots z_k = (Li+Lj)^2 >= 0; trig cubic solve (all real);
// L = copysign(.5,-q)*{s1+s2+s3, s1-s2-s3, s2-s1-s3, s3-s1-s2} + m,
// s_k = sqrt(max(z_k,0)). Guards: sqrt args clamped, acos arg clamped,
// rcp(2R^3+1e-30); B==0 -> all roots m (verified).

__global__ __launch_bounds__(256, 8) void eig4_closed_kernel(
    const float* __restrict__ E1,
    const float* __restrict__ E2,
    const float* __restrict__ C,
    float* __restrict__ out,
    int B)
{
    int i = blockIdx.x * blockDim.x + threadIdx.x;
    if (i >= B) return;

    // Coalesced 8B loads (aligned for every i).
    float2 e1 = *reinterpret_cast<const float2*>(E1 + 2 * i);
    float2 e2 = *reinterpret_cast<const float2*>(E2 + 2 * i);
    const float2* c2 = reinterpret_cast<const float2*>(C + 6 * i);
    float2 ca = c2[0];
    float2 cb = c2[1];
    float2 cc = c2[2];
    float o01 = ca.x, o02 = ca.y, o03 = cb.x;
    float o12 = cb.y, o13 = cc.x, o23 = cc.y;

    // Shift to traceless: B = H - m I.
    float m = (e1.x + e1.y + e2.x + e2.y) * 0.25f;
    float b0 = e1.x - m, b1 = e1.y - m, b2 = e2.x - m, b3 = e2.y - m;

    // Invariants. p = -tr(B^2)/2.
    float q01 = o01 * o01, q02 = o02 * o02, q03 = o03 * o03;
    float q12 = o12 * o12, q13 = o13 * o13, q23 = o23 * o23;
    float soff = q01 + q02 + q03 + q12 + q13 + q23;
    float b0s = b0 * b0, b1s = b1 * b1, b2s = b2 * b2, b3s = b3 * b3;
    float tr2 = b0s + b1s + b2s + b3s + 2.0f * soff;
    float p = -0.5f * tr2;

    // q = -tr(B^3)/3; tr(B^3) = sum bi^3 + 3 sum (bi+bj) oij^2 + 6 (triangles)
    float cub = b0s * b0 + b1s * b1 + b2s * b2 + b3s * b3;
    float mix = (b0 + b1) * q01 + (b0 + b2) * q02 + (b0 + b3) * q03
              + (b1 + b2) * q12 + (b1 + b3) * q13 + (b2 + b3) * q23;
    float tri = o01 * o02 * o12 + o01 * o03 * o13
              + o02 * o03 * o23 + o12 * o13 * o23;
    float tr3 = cub + 3.0f * mix + 6.0f * tri;
    float q = -tr3 * (1.0f / 3.0f);

    // r = det(B), cofactor expansion with CSE (R9-verified).
    float A1 = fmaf(b2, b3, -q23);
    float A2 = fmaf(o12, b3, -(o23 * o13));
    float A3 = fmaf(-b2, o13, o12 * o23);
    float A4 = fmaf(o02, b3, -(o23 * o03));
    float A5 = fmaf(-b2, o03, o02 * o23);
    float A6 = fmaf(o02, o13, -(o12 * o03));
    float M00 = b1 * A1 - o12 * A2 + o13 * A3;
    float M01 = o01 * A1 - o12 * A4 + o13 * A5;
    float M02 = o01 * A2 - b1 * A4 + o13 * A6;
    float M03 = o01 * A3 - b1 * A5 + o12 * A6;
    float r = b0 * M00 - o01 * M01 + o02 * M02 - o03 * M03;

    // Depressed resolvent cubic: w^3 + P w + Q, z = w - 2p/3. All roots real.
    float pp = p * p;
    float P = fmaf(pp, -(1.0f / 3.0f), -4.0f * r);
    float Q = fmaf(p, fmaf(pp, -(2.0f / 27.0f), (8.0f / 3.0f) * r), -(q * q));
    float R2 = fmaxf(P * (-1.0f / 3.0f), 0.0f);
    float R = __builtin_amdgcn_sqrtf(R2);
    float R3 = R2 * R;
    // t = cos(3 phi) = -Q / (2 R^3), guarded for R == 0.
    float t = -Q * __builtin_amdgcn_rcpf(fmaf(2.0f, R3, 1e-30f));
    t = fminf(fmaxf(t, -1.0f), 1.0f);

    // acos(t) via Hastings (A&S 4.4.46): acos(x) = sqrt(1-x) P7(x), x in [0,1],
    // |err| <= 2e-8 rad; reflection acos(t) = pi - acos(-t) for t < 0.
    float x = fabsf(t);
    float sq = __builtin_amdgcn_sqrtf(fmaxf(1.0f - x, 0.0f));
    float pol = fmaf(x, -0.0012624911f, 0.0066700901f);
    pol = fmaf(x, pol, -0.0170881256f);
    pol = fmaf(x, pol, 0.0308918810f);
    pol = fmaf(x, pol, -0.0501743046f);
    pol = fmaf(x, pol, 0.0889789874f);
    pol = fmaf(x, pol, -0.2145988016f);
    pol = fmaf(x, pol, 1.5707963050f);
    float ap = sq * pol;                       // acos(|t|) in [0, pi/2]
    float ac = (t >= 0.0f) ? ap : (3.14159265f - ap);

    // phi = ac/3; HW trig wants revolutions: phi_rev = ac/(6 pi) in [0, 1/6].
    float phi_rev = ac * 0.05305164769f;       // 1/(6*pi)
    float cph = __builtin_amdgcn_cosf(phi_rev);
    float sph = __builtin_amdgcn_sinf(phi_rev);

    float Rc = R * cph;
    float Rs = R * sph * 1.7320508f;           // sqrt(3) R sin(phi)
    float u0 = p * (-2.0f / 3.0f);
    float z1 = fmaf(2.0f, Rc, u0);             // 2 R cos(phi) - 2p/3
    float z2 = u0 - Rc - Rs;                   // 2 R cos(phi + 2pi/3) - 2p/3
    float z3 = u0 - Rc + Rs;                   // 2 R cos(phi - 2pi/3) - 2p/3
    float s1 = __builtin_amdgcn_sqrtf(fmaxf(z1, 0.0f));
    float s2 = __builtin_amdgcn_sqrtf(fmaxf(z2, 0.0f));
    float s3 = __builtin_amdgcn_sqrtf(fmaxf(z3, 0.0f));

    // Quartic roots: sign triples with product = -sign(q).
    float hh = copysignf(0.5f, -q);
    float w = fmaf(hh, s1 + s2 + s3, m);
    float xx = fmaf(hh, s1 - s2 - s3, m);
    float y = fmaf(hh, s2 - s1 - s3, m);
    float z = fmaf(hh, s3 - s1 - s2, m);

    // Ascending sort, 5-comparator network.
#define CSWAP(u, v) { float lo = fminf(u, v), hi = fmaxf(u, v); u = lo; v = hi; }
    CSWAP(w, xx); CSWAP(y, z); CSWAP(w, y); CSWAP(xx, z); CSWAP(xx, y);
#undef CSWAP

    *reinterpret_cast<float4*>(out + 4 * i) = make_float4(w, xx, y, z);
}

extern "C" void kernel_launch(void* const* d_in, const int* in_sizes, int n_in,
                              void* d_out, int out_size, void* d_ws, size_t ws_size,
                              hipStream_t stream)
{
    const float* E1 = (const float*)d_in[0];
    const float* E2 = (const float*)d_in[1];
    const float* C  = (const float*)d_in[2];
    float* out = (float*)d_out;

    int B = in_sizes[0] / 2;  // E1 is [B, 2]
    int block = 256;
    int grid = (B + block - 1) / block;
    eig4_closed_kernel<<<grid, block, 0, stream>>>(E1, E2, C, out, B);
}